// Round 13
// baseline (832.341 us; speedup 1.0000x reference)
//
#include <hip/hip_runtime.h>
#include <hip/hip_fp16.h>
#include <math.h>

// DeeperGCN on MI355X. N=50000, E=625000, D=128, L=7.
// FUSED per-layer kernel: wave w aggregates the exact 16 nodes whose t-rows
// it needs as MFMA B-fragments, parks them in LDS (per-wave scratch -> no
// barrier), then runs the MFMA GEMM + bias/res/LN(+ReLU) epilogue.
// fp16 streams; tables pre-scaled by log2(e); direct-exp softmax; 16-edge
// burst gather. No t16 global round-trip, no degree sort.

constexpr int D = 128;
constexpr int NA = 9;   // atom feats
constexpr int NB = 3;   // bond feats
constexpr float L2E = 1.4426950408889634f;   // log2(e)
constexpr float INV_L2E = 0.6931471805599453f;

using half8  = __attribute__((ext_vector_type(8))) _Float16;
using h2v    = __attribute__((ext_vector_type(2))) _Float16;
using floatx4 = __attribute__((ext_vector_type(4))) float;

// ------------------------- CSR build -------------------------

__global__ void k_hist(const int* __restrict__ dst, int* __restrict__ deg, int E) {
    int e = blockIdx.x * 256 + threadIdx.x;
    if (e < E) atomicAdd(&deg[dst[e]], 1);
}

__global__ void k_scan_a(const int* __restrict__ deg, int* __restrict__ offs,
                         int* __restrict__ bsum, int N) {
    __shared__ int s[256];
    int i = blockIdx.x * 256 + threadIdx.x;
    int v = (i < N) ? deg[i] : 0;
    s[threadIdx.x] = v;
    __syncthreads();
    for (int d = 1; d < 256; d <<= 1) {
        int add = (threadIdx.x >= d) ? s[threadIdx.x - d] : 0;
        __syncthreads();
        s[threadIdx.x] += add;
        __syncthreads();
    }
    if (i < N) offs[i + 1] = s[threadIdx.x];
    if (threadIdx.x == 255) bsum[blockIdx.x] = s[255];
    if (i == 0) offs[0] = 0;
}

// nb must be <= 256 (N=50000 -> nb=196)
__global__ void k_scan_b(const int* __restrict__ bsum, int* __restrict__ bexc, int nb) {
    __shared__ int s[256];
    int t = threadIdx.x;
    int v = (t < nb) ? bsum[t] : 0;
    s[t] = v;
    __syncthreads();
    for (int d = 1; d < 256; d <<= 1) {
        int add = (t >= d) ? s[t - d] : 0;
        __syncthreads();
        s[t] += add;
        __syncthreads();
    }
    if (t < nb) bexc[t] = s[t] - v;  // exclusive block prefix
}

__global__ void k_scan_c(int* __restrict__ offs, const int* __restrict__ bexc, int N) {
    int i = blockIdx.x * 256 + threadIdx.x;
    if (i < N) offs[i + 1] += bexc[blockIdx.x];
}

__global__ void k_fill(const int* __restrict__ src, const int* __restrict__ dst,
                       const int* __restrict__ attr, const int* __restrict__ offs,
                       int* __restrict__ cur, int2* __restrict__ recs, int E) {
    int e = blockIdx.x * 256 + threadIdx.x;
    if (e >= E) return;
    int d = dst[e];
    int pos = offs[d] + atomicAdd(&cur[d], 1);
    int cidx = attr[e * 3] * 64 + attr[e * 3 + 1] * 8 + attr[e * 3 + 2];
    recs[pos] = make_int2(src[e], cidx);
}

// comb16[c][d] = fp16(L2E * (b0[c>>6][d] + b1[(c>>3)&7][d] + b2[c&7][d]))
__global__ void k_comb(const float* __restrict__ bemb, __half* __restrict__ comb16) {
    int gid = blockIdx.x * 256 + threadIdx.x;  // 512*32 float4s
    int c = gid >> 5, q = gid & 31;
    int a0 = c >> 6, a1 = (c >> 3) & 7, a2 = c & 7;
    float4 v0 = *(const float4*)(bemb + (a0)*D + q * 4);
    float4 v1 = *(const float4*)(bemb + (8 + a1) * D + q * 4);
    float4 v2 = *(const float4*)(bemb + (16 + a2) * D + q * 4);
    __half2* c2 = (__half2*)comb16;
    c2[c * 64 + q * 2]     = __floats2half2_rn(L2E * (v0.x + v1.x + v2.x),
                                               L2E * (v0.y + v1.y + v2.y));
    c2[c * 64 + q * 2 + 1] = __floats2half2_rn(L2E * (v0.z + v1.z + v2.z),
                                               L2E * (v0.w + v1.w + v2.w));
}

// Wt16[l][f][k] = fp16(W[l][k][f])  -- K-major transposed fp16 weights
__global__ void k_wt(const float* __restrict__ W, __half* __restrict__ Wt16, int total) {
    int o = blockIdx.x * 256 + threadIdx.x;
    if (o >= total) return;
    int l = o >> 14;          // /(128*128)
    int rem = o & 16383;
    int f = rem >> 7, k = rem & 127;
    Wt16[o] = __float2half_rn(W[(l << 14) + k * 128 + f]);
}

// ------------------------- Atom encoder (scaled h16) -------------------------

__global__ void k_atom(const int* __restrict__ x, const float* __restrict__ aemb,
                       __half* __restrict__ h16, int N) {
    int wid = (blockIdx.x * blockDim.x + threadIdx.x) >> 6;
    int lane = threadIdx.x & 63;
    if (wid >= N) return;
    const int* xr = x + wid * NA;
    float ax = 0.f, ay = 0.f;
#pragma unroll
    for (int f = 0; f < NA; ++f) {
        int v = xr[f];  // wave-uniform broadcast
        const float2 e = *(const float2*)(aemb + (f * 64 + v) * D + 2 * lane);
        ax += e.x; ay += e.y;
    }
    ((__half2*)h16)[wid * 64 + lane] = __floats2half2_rn(ax * L2E, ay * L2E);
}

// ------------------------- FUSED layer: agg + MFMA GEMM + LN ----------------
// Block = 256 threads = 4 waves, 64 nodes. Wave w handles nodes
// m0 + w*16 + j (j=0..15): aggregates each (16-edge burst pipeline, tables
// pre-scaled by L2E, direct exp2), writes the t-row to its private LDS rows
// (stride 136 halves -> only 2-way bank aliasing), then computes
// D[f][node] = sum_k Wt16[f][k]*t[node][k] via v_mfma_f32_16x16x32_f16
// (B-frag read straight from its own LDS rows -- no barrier needed).
// MODE 0: hres16 = o (fp16); h16 = fp16(L2E*relu(LN(o))).
// MODE 1: out = LN(o) fp32.

template <int MODE>
__global__ __launch_bounds__(256) void k_layer(const __half* __restrict__ h16in,
                                               const int2* __restrict__ recs,
                                               const int* __restrict__ offs,
                                               const __half* __restrict__ comb16,
                                               const __half* __restrict__ Wt16,
                                               const float* __restrict__ bl,
                                               const __half* __restrict__ res16,
                                               __half* __restrict__ hres16,
                                               const float* __restrict__ g,
                                               const float* __restrict__ bta,
                                               __half* __restrict__ h16out,
                                               float* __restrict__ out,
                                               int N, int useRes) {
    __shared__ alignas(16) _Float16 tlds[64 * 136];  // 17.4 KB, row stride 136

    int lane = threadIdx.x & 63;
    int wave = threadIdx.x >> 6;
    int quad = lane >> 4, col = lane & 15;
    int m0 = blockIdx.x * 64;
    int base = m0 + wave * 16;

    const h2v* hrow = (const h2v*)h16in + lane;    // row r at hrow[r*64]
    const h2v* crow = (const h2v*)comb16 + lane;
    const h2v zero2 = (h2v)(_Float16)0;
    const h2v eps2  = {(_Float16)(1e-7f * L2E), (_Float16)(1e-7f * L2E)};

    // ---------------- Phase A: aggregate this wave's 16 nodes ----------------
    for (int j = 0; j < 16; ++j) {
        int nid = base + j;
        float tx = 0.f, ty = 0.f;
        if (nid < N) {
            int su = __builtin_amdgcn_readfirstlane(offs[nid]);
            int eu = __builtin_amdgcn_readfirstlane(offs[nid + 1]);
            h2v hm2 = hrow[nid * 64];
            float hsx = (float)hm2[0], hsy = (float)hm2[1];
            if (su >= eu) {
                tx = hsx * INV_L2E; ty = hsy * INV_L2E;
            } else {
                float Sx = 0.f, Sy = 0.f, Wx = 0.f, Wy = 0.f;
                int last = eu - 1;
                h2v hq[16], cq[16];
                auto load4 = [&](int b4, int slot) {
#pragma unroll
                    for (int i = 0; i < 4; ++i) {
                        int idx = b4 + i; idx = (idx < last) ? idx : last;
                        int2 rr = recs[idx];
                        int sj = __builtin_amdgcn_readfirstlane(rr.x);
                        int cj = __builtin_amdgcn_readfirstlane(rr.y);
                        hq[slot * 4 + i] = hrow[sj * 64];
                        cq[slot * 4 + i] = crow[cj * 64];
                    }
                };
                auto comp4u = [&](int slot) {
#pragma unroll
                    for (int i = 0; i < 4; ++i) {
                        h2v m = hq[slot * 4 + i] + cq[slot * 4 + i];
                        m = __builtin_elementwise_max(m, zero2);
                        m = m + eps2;
                        float u0 = (float)m[0], u1 = (float)m[1];
                        float px = __builtin_amdgcn_exp2f(u0);
                        float py = __builtin_amdgcn_exp2f(u1);
                        Sx += px; Sy += py;
                        Wx = fmaf(px, u0, Wx);
                        Wy = fmaf(py, u1, Wy);
                    }
                };
                auto comp4m = [&](int gb, int slot) {
#pragma unroll
                    for (int i = 0; i < 4; ++i) {
                        h2v m = hq[slot * 4 + i] + cq[slot * 4 + i];
                        m = __builtin_elementwise_max(m, zero2);
                        m = m + eps2;
                        float u0 = (float)m[0], u1 = (float)m[1];
                        bool valid = (gb + i) < eu;  // wave-uniform
                        float px = valid ? __builtin_amdgcn_exp2f(u0) : 0.f;
                        float py = valid ? __builtin_amdgcn_exp2f(u1) : 0.f;
                        Sx += px; Sy += py;
                        Wx = fmaf(px, u0, Wx);
                        Wy = fmaf(py, u1, Wy);
                    }
                };
                load4(su, 0);
                if (su + 4  < eu) load4(su + 4, 1);
                if (su + 8  < eu) load4(su + 8, 2);
                if (su + 12 < eu) load4(su + 12, 3);
                int e = su;
                for (; e + 16 < eu; e += 16) {
                    comp4u(0); comp4u(1); comp4u(2); comp4u(3);
                    load4(e + 16, 0); load4(e + 20, 1);
                    load4(e + 24, 2); load4(e + 28, 3);
                }
                comp4m(e, 0);
                if (e + 4  < eu) comp4m(e + 4, 1);
                if (e + 8  < eu) comp4m(e + 8, 2);
                if (e + 12 < eu) comp4m(e + 12, 3);
                tx = (hsx + Wx / (Sx + 1e-16f)) * INV_L2E;
                ty = (hsy + Wy / (Sy + 1e-16f)) * INV_L2E;
            }
        }
        // park t-row in this wave's LDS scratch (lane holds feats 2l,2l+1)
        h2v tv = {(_Float16)tx, (_Float16)ty};
        *(h2v*)(tlds + (wave * 16 + j) * 136 + lane * 2) = tv;
    }

    // ---------------- Phase B: MFMA GEMM (B-frag from own LDS rows) ----------
    int node = base + col;
    bool nok = node < N;
    int nc = nok ? node : N - 1;

    const _Float16* trow = tlds + (wave * 16 + col) * 136;
    half8 bfrag[4];
#pragma unroll
    for (int ks = 0; ks < 4; ++ks)
        bfrag[ks] = *(const half8*)(trow + ks * 32 + quad * 8);

    floatx4 acc[8];
#pragma unroll
    for (int ft = 0; ft < 8; ++ft) acc[ft] = (floatx4){0.f, 0.f, 0.f, 0.f};

#pragma unroll
    for (int ft = 0; ft < 8; ++ft) {
        const __half* wrow = Wt16 + (size_t)(ft * 16 + col) * 128;  // A-op: m=f
#pragma unroll
        for (int ks = 0; ks < 4; ++ks) {
            half8 afrag = *(const half8*)(wrow + ks * 32 + quad * 8);
            acc[ft] = __builtin_amdgcn_mfma_f32_16x16x32_f16(afrag, bfrag[ks],
                                                             acc[ft], 0, 0, 0);
        }
    }

    float s = 0.f, ss = 0.f;
#pragma unroll
    for (int ft = 0; ft < 8; ++ft) {
        int f0 = ft * 16 + quad * 4;  // 4 consecutive features per lane
        float4 bb = *(const float4*)(bl + f0);
        float o0 = acc[ft][0] + bb.x, o1 = acc[ft][1] + bb.y;
        float o2 = acc[ft][2] + bb.z, o3 = acc[ft][3] + bb.w;
        if (useRes) {
            uint2 rr = *(const uint2*)(res16 + (size_t)nc * 128 + f0);
            __half2 r01 = *(__half2*)&rr.x, r23 = *(__half2*)&rr.y;
            o0 += __low2float(r01); o1 += __high2float(r01);
            o2 += __low2float(r23); o3 += __high2float(r23);
        }
        acc[ft][0] = o0; acc[ft][1] = o1; acc[ft][2] = o2; acc[ft][3] = o3;
        s += (o0 + o1) + (o2 + o3);
        ss += fmaf(o0, o0, o1 * o1) + fmaf(o2, o2, o3 * o3);
        if (MODE == 0 && nok) {
            __half2 h01 = __floats2half2_rn(o0, o1);
            __half2 h23 = __floats2half2_rn(o2, o3);
            uint2 pk = make_uint2(*(unsigned*)&h01, *(unsigned*)&h23);
            *(uint2*)(hres16 + (size_t)node * 128 + f0) = pk;
        }
    }
    s += __shfl_xor(s, 16, 64);  ss += __shfl_xor(ss, 16, 64);
    s += __shfl_xor(s, 32, 64);  ss += __shfl_xor(ss, 32, 64);
    float mu = s * (1.f / 128.f);
    float var = ss * (1.f / 128.f) - mu * mu;
    float rs = rsqrtf(var + 1e-5f);

#pragma unroll
    for (int ft = 0; ft < 8; ++ft) {
        int f0 = ft * 16 + quad * 4;
        float4 gg = *(const float4*)(g + f0);
        float4 bt = *(const float4*)(bta + f0);
        float l0 = (acc[ft][0] - mu) * rs * gg.x + bt.x;
        float l1 = (acc[ft][1] - mu) * rs * gg.y + bt.y;
        float l2 = (acc[ft][2] - mu) * rs * gg.z + bt.z;
        float l3 = (acc[ft][3] - mu) * rs * gg.w + bt.w;
        if (MODE == 0) {
            l0 = fmaxf(l0, 0.f); l1 = fmaxf(l1, 0.f);
            l2 = fmaxf(l2, 0.f); l3 = fmaxf(l3, 0.f);
            if (nok) {
                __half2 h01 = __floats2half2_rn(l0 * L2E, l1 * L2E);
                __half2 h23 = __floats2half2_rn(l2 * L2E, l3 * L2E);
                uint2 pk = make_uint2(*(unsigned*)&h01, *(unsigned*)&h23);
                *(uint2*)(h16out + (size_t)node * 128 + f0) = pk;
            }
        } else {
            if (nok)
                *(float4*)(out + (size_t)node * 128 + f0) =
                    make_float4(l0, l1, l2, l3);
        }
    }
}

// ------------------------- Launch -------------------------

extern "C" void kernel_launch(void* const* d_in, const int* in_sizes, int n_in,
                              void* d_out, int out_size, void* d_ws, size_t ws_size,
                              hipStream_t stream) {
    const int*   x    = (const int*)d_in[0];
    const int*   ei   = (const int*)d_in[1];
    const int*   attr = (const int*)d_in[2];
    const float* aemb = (const float*)d_in[3];
    const float* bemb = (const float*)d_in[4];
    const float* Wf   = (const float*)d_in[5];
    const float* bf   = (const float*)d_in[6];
    const float* gam  = (const float*)d_in[7];
    const float* bet  = (const float*)d_in[8];
    float* out = (float*)d_out;

    const int N = in_sizes[0] / NA;        // 50000
    const int E = in_sizes[1] / 2;         // 625000
    const int L = in_sizes[5] / (D * D);   // 7

    char* ws = (char*)d_ws;
    size_t o = 0;
    auto carve = [&](size_t bytes) -> void* {
        void* p = (void*)(ws + o);
        o += (bytes + 255) & ~(size_t)255;
        return p;
    };
    __half* hres16 = (__half*)carve((size_t)N * D * 2);  // fp16 residual chain
    __half* hA16   = (__half*)carve((size_t)N * D * 2);  // fp16 gather table A (x L2E)
    __half* hB16   = (__half*)carve((size_t)N * D * 2);  // fp16 gather table B (x L2E)
    int2*   recs   = (int2*)carve((size_t)E * 8);
    __half* comb16 = (__half*)carve(512 * D * 2);
    __half* Wt16   = (__half*)carve((size_t)L * D * D * 2);
    int*    deg    = (int*)carve((size_t)N * 4);
    int*    cur    = (int*)carve((size_t)N * 4);   // contiguous after deg
    int*    offs   = (int*)carve((size_t)(N + 1) * 4);
    int*    bsum   = (int*)carve(4096);
    int*    bexc   = (int*)carve(4096);

    const int* src = ei;
    const int* dst = ei + E;

    size_t degRound = ((size_t)N * 4 + 255) & ~(size_t)255;
    hipMemsetAsync(deg, 0, degRound * 2, stream);  // zeros deg AND cur

    int ebl = (E + 255) / 256;
    int nbl = (N + 255) / 256;  // 196 (<=256 required by k_scan_b)
    k_comb<<<64, 256, 0, stream>>>(bemb, comb16);
    int wtot = L * D * D;
    k_wt<<<(wtot + 255) / 256, 256, 0, stream>>>(Wf, Wt16, wtot);
    k_hist<<<ebl, 256, 0, stream>>>(dst, deg, E);
    k_scan_a<<<nbl, 256, 0, stream>>>(deg, offs, bsum, N);
    k_scan_b<<<1, 256, 0, stream>>>(bsum, bexc, nbl);
    k_scan_c<<<nbl, 256, 0, stream>>>(offs, bexc, N);
    k_fill<<<ebl, 256, 0, stream>>>(src, dst, attr, offs, cur, recs, E);

    int wbl = (N * 64 + 255) / 256;  // wave per node
    k_atom<<<wbl, 256, 0, stream>>>(x, aemb, hA16, N);

    int gbl = (N + 63) / 64;  // 782 blocks, 64 nodes each
    for (int l = 0; l < L; ++l) {
        const __half* hin  = (l & 1) ? hB16 : hA16;
        __half*       hout = (l & 1) ? hA16 : hB16;
        if (l == L - 1) {
            k_layer<1><<<gbl, 256, 0, stream>>>(hin, recs, offs, comb16,
                                                Wt16 + l * D * D, bf + l * D,
                                                hres16, hres16,
                                                gam + l * D, bet + l * D,
                                                hout, out, N, 1);
        } else {
            k_layer<0><<<gbl, 256, 0, stream>>>(hin, recs, offs, comb16,
                                                Wt16 + l * D * D, bf + l * D,
                                                hres16, hres16,
                                                gam + l * D, bet + l * D,
                                                hout, out, N, l > 0 ? 1 : 0);
        }
    }
}